// Round 14
// baseline (592.403 us; speedup 1.0000x reference)
//
#include <hip/hip_runtime.h>

#define BB 128
#define SS 512
#define TT 513
#define DD 128
#define HH 4
#define LL 4
#define MM (BB*TT)   // 65664

typedef __attribute__((ext_vector_type(4))) float f32x4;
typedef __attribute__((ext_vector_type(16))) float f32x16;
typedef __attribute__((ext_vector_type(8))) short short8;

__device__ __forceinline__ float b2f(ushort u){
  union { uint i; float f; } c; c.i = ((uint)u) << 16; return c.f;
}
__device__ __forceinline__ ushort f2b(float f){
  union { float f; uint i; } c; c.f = f;
  uint x = c.i;
  return (ushort)((x + 0x7fffu + ((x >> 16) & 1u)) >> 16);
}
union S8 { short8 v; ushort u[8]; };

__device__ __forceinline__ uint cvtpk(float lo, float hi){
  uint r;
  asm("v_cvt_pk_bf16_f32 %0, %1, %2" : "=v"(r) : "v"(lo), "v"(hi));
  return r;
}
__device__ __forceinline__ float fexp2(float x){
#if __has_builtin(__builtin_amdgcn_exp2f)
  return __builtin_amdgcn_exp2f(x);
#else
  return exp2f(x);
#endif
}
// bf16-pair dot with f32 accumulate: d = a.lo*b.lo + a.hi*b.hi + c
__device__ __forceinline__ float dot2bf(uint a, uint b, float c){
  float d;
  asm("v_dot2_f32_bf16 %0, %1, %2, %3" : "=v"(d) : "v"(a), "v"(b), "v"(c));
  return d;
}

// ---------------- embed: xb = bf16(t_emb + c_emb + p_emb) ; last token = agg ----------------
__global__ __launch_bounds__(256) void k_embed(
    const float* __restrict__ d_t, const float* __restrict__ d_l, const int* __restrict__ d_emb,
    const float* __restrict__ poi, const float* __restrict__ W_time, const float* __restrict__ W_space,
    const float* __restrict__ agg, ushort* __restrict__ xb)
{
  int gid = blockIdx.x*256 + threadIdx.x;
  if (gid >= MM*DD) return;
  int d = gid & 127;
  int m = gid >> 7;
  int b = m / TT, t = m % TT;
  float v;
  if (t == SS) v = agg[d];
  else {
    int bs = b*SS + t;
    v = d_t[bs]*W_time[d] + d_l[bs*2]*W_space[d*2] + d_l[bs*2+1]*W_space[d*2+1]
        + poi[(size_t)d_emb[bs]*DD + d];
  }
  xb[gid] = f2b(v);
}

// ---------------- f32 -> bf16 convert ----------------
__global__ __launch_bounds__(256) void k_f2b(const float* __restrict__ src, ushort* __restrict__ dst, int n){
  int i = blockIdx.x*256 + threadIdx.x;
  if (i < n) dst[i] = f2b(src[i]);
}

// ---------------- GEMM: C(M,N) = A(M,K) @ W(N,K)^T + bias ----------------
template<bool RELU, bool OUTB>
__global__ __launch_bounds__(256) void k_gemm(
  const ushort* __restrict__ A, const ushort* __restrict__ W,
  const float* __restrict__ bias, void* __restrict__ Cout,
  const int N, const int K)
{
  __shared__ __align__(16) ushort As[64*128], Ws[64*128];
  const int tid = threadIdx.x;
  const int m0 = blockIdx.x * 64, n0 = blockIdx.y * 64;
  const int l = tid & 63, wid = tid >> 6;
  const int wr = wid >> 1, wc = wid & 1;
  const int lr = l & 15, lg = l >> 4;
  f32x4 acc[2][2] = {};
  for (int kt = 0; kt < K; kt += 128){
    if (kt) __syncthreads();
    for (int i = tid; i < 1024; i += 256){
      const int row = i >> 4, ch = i & 15;
      const int bo_ = (ch*16) ^ ((row & 7) << 4);
      *(short8*)((char*)As + row*256 + bo_) = *(const short8*)&A[(size_t)(m0+row)*K + kt + ch*8];
      *(short8*)((char*)Ws + row*256 + bo_) = *(const short8*)&W[(size_t)(n0+row)*K + kt + ch*8];
    }
    __syncthreads();
    #pragma unroll
    for (int k0 = 0; k0 < 128; k0 += 32){
      const int sw = ((k0 + lg*8)*2) ^ ((lr & 7) << 4);
      short8 a0 = *(const short8*)((const char*)As + (wr*32+lr)*256 + sw);
      short8 a1 = *(const short8*)((const char*)As + (wr*32+16+lr)*256 + sw);
      short8 b0 = *(const short8*)((const char*)Ws + (wc*32+lr)*256 + sw);
      short8 b1 = *(const short8*)((const char*)Ws + (wc*32+16+lr)*256 + sw);
      acc[0][0] = __builtin_amdgcn_mfma_f32_16x16x32_bf16(a0, b0, acc[0][0], 0,0,0);
      acc[0][1] = __builtin_amdgcn_mfma_f32_16x16x32_bf16(a0, b1, acc[0][1], 0,0,0);
      acc[1][0] = __builtin_amdgcn_mfma_f32_16x16x32_bf16(a1, b0, acc[1][0], 0,0,0);
      acc[1][1] = __builtin_amdgcn_mfma_f32_16x16x32_bf16(a1, b1, acc[1][1], 0,0,0);
    }
  }
  #pragma unroll
  for (int i=0;i<2;i++)
  #pragma unroll
  for (int j=0;j<2;j++)
  #pragma unroll
  for (int r=0;r<4;r++){
    const int lm = wr*32 + i*16 + lg*4 + r;
    const int ln = wc*32 + j*16 + lr;
    const size_t idx = (size_t)(m0+lm)*N + (n0+ln);
    float v = acc[i][j][r] + bias[n0+ln];
    if (RELU) v = fmaxf(v, 0.f);
    if (OUTB) ((ushort*)Cout)[idx] = f2b(v);
    else ((float*)Cout)[idx] = v;
  }
}

// ---------------- fused GEMM (N=128) + residual(bf16) + LayerNorm ----------------
__global__ __launch_bounds__(256) void k_gemm_ln(
  const ushort* __restrict__ A, const ushort* __restrict__ W,
  const float* __restrict__ bias, ushort* __restrict__ xb,
  const float* __restrict__ g, const float* __restrict__ bb, const int K)
{
  __shared__ __align__(16) ushort As[64*128], Ws[128*128];
  const int tid = threadIdx.x;
  const int m0 = blockIdx.x * 64;
  const int l = tid & 63, w = tid >> 6;
  const int lr = l & 15, lg = l >> 4;
  f32x4 acc[8] = {};
  for (int kt = 0; kt < K; kt += 128){
    if (kt) __syncthreads();
    for (int i = tid; i < 1024; i += 256){
      const int row = i >> 4, ch = i & 15;
      const int bo_ = (ch*16) ^ ((row & 7) << 4);
      *(short8*)((char*)As + row*256 + bo_) = *(const short8*)&A[(size_t)(m0+row)*K + kt + ch*8];
    }
    for (int i = tid; i < 2048; i += 256){
      const int row = i >> 4, ch = i & 15;
      const int bo_ = (ch*16) ^ ((row & 7) << 4);
      *(short8*)((char*)Ws + row*256 + bo_) = *(const short8*)&W[(size_t)row*K + kt + ch*8];
    }
    __syncthreads();
    #pragma unroll
    for (int k0 = 0; k0 < 128; k0 += 32){
      const int sw = ((k0 + lg*8)*2) ^ ((lr & 7) << 4);
      short8 a = *(const short8*)((const char*)As + (w*16+lr)*256 + sw);
      #pragma unroll
      for (int j=0;j<8;j++){
        short8 bf = *(const short8*)((const char*)Ws + (j*16+lr)*256 + sw);
        acc[j] = __builtin_amdgcn_mfma_f32_16x16x32_bf16(a, bf, acc[j], 0,0,0);
      }
    }
  }
  float biasj[8], gj[8], bj[8];
  #pragma unroll
  for (int j=0;j<8;j++){ biasj[j]=bias[j*16+lr]; gj[j]=g[j*16+lr]; bj[j]=bb[j*16+lr]; }
  #pragma unroll
  for (int r=0;r<4;r++){
    const size_t row = (size_t)(m0 + w*16 + lg*4 + r);
    float resid[8], s=0.f, sq=0.f;
    #pragma unroll
    for (int j=0;j<8;j++){
      float v = acc[j][r] + biasj[j];
      resid[j] = b2f(xb[row*128 + j*16 + lr]) + v;
      s += resid[j]; sq += resid[j]*resid[j];
    }
    #pragma unroll
    for (int off=1; off<16; off<<=1){ s += __shfl_xor(s,off,64); sq += __shfl_xor(sq,off,64); }
    const float mean = s*(1.f/128.f);
    const float var  = fmaxf(sq*(1.f/128.f) - mean*mean, 0.f);
    const float rstd = rsqrtf(var + 1e-5f);
    #pragma unroll
    for (int j=0;j<8;j++){
      float o = (resid[j]-mean)*rstd*gj[j] + bj[j];
      xb[row*128 + j*16 + lr] = f2b(o);
    }
  }
}

// ---------------- flash attention v5b: K+V in LDS, 1 block per (b,h), 8 waves ----------------
#define VSTRIDE 544
#define NEGM 30000.f
#define MFMA32(a,b,c) __builtin_amdgcn_mfma_f32_32x32x16_bf16(a,b,c,0,0,0)

__global__ __launch_bounds__(512) void k_attn(const ushort* __restrict__ qkv, ushort* __restrict__ ao)
{
  __shared__ __align__(16) ushort KL[VSTRIDE*32];  // [t][d], swizzled
  __shared__ __align__(16) ushort VT[32*VSTRIDE];  // [d][t], swizzled
  const int tid = threadIdx.x;
  const int b = blockIdx.x >> 2, h = blockIdx.x & 3;
  const size_t base = (size_t)b*TT*384 + h*32;
  union { short4 v; ushort u[4]; } sv;
  for (int i = tid; i < 8*VSTRIDE; i += 512){
    int t = i >> 3, dc = (i & 7)*4;
    sv.u[0]=0; sv.u[1]=0; sv.u[2]=0; sv.u[3]=0;
    if (t < TT) sv.v = *(const short4*)&qkv[base + (size_t)t*384 + 128 + dc];
    *(short4*)((char*)KL + ((t*64 + dc*2) ^ ((t&7)<<4))) = sv.v;
  }
  for (int i = tid; i < 8*VSTRIDE; i += 512){
    int t = i >> 3, dc = (i & 7)*4;
    sv.u[0]=0; sv.u[1]=0; sv.u[2]=0; sv.u[3]=0;
    if (t < TT) sv.v = *(const short4*)&qkv[base + (size_t)t*384 + 256 + dc];
    #pragma unroll
    for (int e=0;e<4;e++){
      int d = dc + e;
      *(ushort*)((char*)VT + ((d*1088 + t*2) ^ ((d&7)<<4))) = sv.u[e];
    }
  }
  __syncthreads();
  const int l = tid & 63, w = tid >> 6;
  const int lq = l & 31, hi = l >> 5;
  const float qscale = 0.25503486341f;   // 1/sqrt(32) * log2(e)
  const int krow = (lq & 3) | ((lq & 4) << 1) | ((lq & 8) >> 1) | (lq & 16);
  f32x16 cinit;
  #pragma unroll
  for (int r=0;r<16;r++) cinit[r] = -40.f;   // fixed softmax max (exp2 domain)

  for (int qi = 0; qi < 3; qi++){
    const int qb = w + qi*8;
    if (qb >= 17) break;
    const int q0 = qb*32;
    int qrow = q0 + lq; if (qrow > SS) qrow = SS;
    S8 qa, qf0, qf1;
    qa.v = *(const short8*)&qkv[base + (size_t)qrow*384 + hi*8];
    #pragma unroll
    for (int j=0;j<8;j++) qf0.u[j] = f2b(b2f(qa.u[j]) * qscale);
    qa.v = *(const short8*)&qkv[base + (size_t)qrow*384 + 16 + hi*8];
    #pragma unroll
    for (int j=0;j<8;j++) qf1.u[j] = f2b(b2f(qa.u[j]) * qscale);

    float rsl = 0.f;
    f32x16 acc = {};
    int t0 = 0;
    for (int kb = 0; kb < 17; kb++, t0 += 32){
      const int trow = t0 + krow;
      short8 kc0 = *(const short8*)((const char*)KL + ((trow*64 + hi*16)      ^ ((trow&7)<<4)));
      short8 kc1 = *(const short8*)((const char*)KL + ((trow*64 + 32 + hi*16) ^ ((trow&7)<<4)));
      f32x16 s = MFMA32(kc0, qf0.v, cinit);
      s = MFMA32(kc1, qf1.v, s);
      if (t0 + 32 > TT){
        #pragma unroll
        for (int r=0;r<16;r++){
          const int key = t0 + (r&7) + 8*hi + 16*(r>>3);
          if (key >= TT) s[r] = -NEGM;
        }
      }
      float p[16];
      #pragma unroll
      for (int r=0;r<16;r++){ p[r] = fexp2(s[r]); rsl += p[r]; }
      union { short8 v; uint u[4]; } pa0, pa1;
      #pragma unroll
      for (int wd=0; wd<4; wd++){
        pa0.u[wd] = cvtpk(p[2*wd],   p[2*wd+1]);
        pa1.u[wd] = cvtpk(p[8+2*wd], p[8+2*wd+1]);
      }
      short8 v0 = *(const short8*)((const char*)VT + (((lq*1088) + (t0 + hi*8)*2)      ^ ((lq&7)<<4)));
      short8 v1 = *(const short8*)((const char*)VT + (((lq*1088) + (t0 + 16 + hi*8)*2) ^ ((lq&7)<<4)));
      acc = MFMA32(v0, pa0.v, acc);
      acc = MFMA32(v1, pa1.v, acc);
    }
    rsl += __shfl_xor(rsl, 32, 64);   // merge partner half's key sum (same q)
    if (q0 + lq < TT){
      const float inv = 1.f / rsl;
      ushort* orow = ao + ((size_t)(b*TT + q0 + lq))*DD + h*32;
      #pragma unroll
      for (int r=0;r<16;r++){
        const int d = (r&3) + 8*(r>>2) + 4*hi;
        orow[d] = f2b(acc[r]*inv);
      }
    }
  }
}

// ---------------- ctx extraction + gamma/tau heads (ctx from bf16 x) ----------------
__global__ __launch_bounds__(256) void k_ctx(
    const ushort* __restrict__ xb, const float* __restrict__ Wg, const float* __restrict__ bg,
    const float* __restrict__ Wt, const float* __restrict__ bt,
    float* __restrict__ out, float* __restrict__ ctxws)
{
  __shared__ float cs[128];
  const int b = blockIdx.x, tid = threadIdx.x;
  const ushort* xr = &xb[((size_t)b*TT + SS)*128];
  if (tid < 128){
    float v = b2f(xr[tid]);
    cs[tid] = v;
    out[(size_t)b*419 + 34 + tid] = v;
    ctxws[b*128 + tid] = v;
  }
  __syncthreads();
  const int j = tid & 127;
  const float* Wrow = (tid < 128) ? &Wg[(size_t)j*128] : &Wt[(size_t)j*128];
  float acc = 0.f;
  #pragma unroll 8
  for (int d=0; d<128; d+=4){
    float4 wv = *(const float4*)&Wrow[d];
    acc += cs[d]*wv.x + cs[d+1]*wv.y + cs[d+2]*wv.z + cs[d+3]*wv.w;
  }
  if (tid < 128){
    out[(size_t)b*419 + 162 + j] = acc + bg[j];
  } else {
    float tv = acc + bt[j];
    float sp = fmaxf(tv, 0.f) + log1pf(__expf(-fabsf(tv)));
    out[(size_t)b*419 + 290 + j] = sp;
  }
}

// ---------------- GRU decoder v6: Whh bf16 in LDS, 272B row stride (conflict-free b128) ----
// Per step each thread reads its 256B row via 16 ds_read_b128 (quad index (17*tid+i)%8
// covers all 8 bank-quads uniformly) + 64 v_dot2_f32_bf16 with 4-way split accumulators.
// LDS throughput-bound (~98KB/step), no VGPR-resident weights -> no spill fight.
#define GRSTR 272   // bytes per WL row = 17*16 (odd quad count -> full bank coverage)
__global__ __launch_bounds__(384) void k_gru(
    const float* __restrict__ ctx, const ushort* __restrict__ whh_b,
    const float* __restrict__ bih, const float* __restrict__ bhh,
    const float* __restrict__ Wfc, const float* __restrict__ bfc,
    float* __restrict__ deltas)
{
  __shared__ __align__(16) char WL[384*GRSTR];   // 104448 B
  __shared__ uint hs2[64];
  __shared__ float gh[384], red[2];
  const int b = blockIdx.x, tid = threadIdx.x;
  // stage Whh bf16 -> LDS (16B chunks, coalesced global reads)
  for (int i = tid; i < 384*16; i += 384){
    const int row = i >> 4, ch = i & 15;
    *(short8*)(WL + row*GRSTR + ch*16) = *(const short8*)&whh_b[(size_t)row*128 + ch*8];
  }
  const float bhh_t = bhh[tid];
  float bih0=0.f, bih1=0.f, bih2=0.f, wfc_t=0.f;
  if (tid < 128){ bih0=bih[tid]; bih1=bih[128+tid]; bih2=bih[256+tid]; wfc_t=Wfc[tid]; }
  const float bfc0 = bfc[0];
  float hcur = (tid < 128) ? ctx[b*128 + tid] : 0.f;
  {
    float hn1 = __shfl_down(hcur, 1, 64);
    if (tid < 128 && !(tid & 1)) hs2[tid>>1] = (uint)f2b(hcur) | (((uint)f2b(hn1)) << 16);
  }
  const uint4* wrow = (const uint4*)(WL + tid*GRSTR);
  for (int step=0; step<32; step++){
    __syncthreads();                       // hs2 + WL visible to all waves
    float a0=0.f, a1=0.f, a2=0.f, a3=0.f;
    #pragma unroll
    for (int i=0;i<16;i++){
      uint4 wv = wrow[i];                  // ds_read_b128, conflict-free
      a0 = dot2bf(wv.x, hs2[i*4+0], a0);
      a1 = dot2bf(wv.y, hs2[i*4+1], a1);
      a2 = dot2bf(wv.z, hs2[i*4+2], a2);
      a3 = dot2bf(wv.w, hs2[i*4+3], a3);
    }
    gh[tid] = bhh_t + ((a0+a1)+(a2+a3));
    __syncthreads();
    if (tid < 128){
      float r = 1.f/(1.f + __expf(-(bih0 + gh[tid])));
      float z = 1.f/(1.f + __expf(-(bih1 + gh[128+tid])));
      float n = tanhf(bih2 + r*gh[256+tid]);
      float hn = (1.f - z)*n + z*hcur;
      hcur = hn;
      float hn1 = __shfl_down(hn, 1, 64);
      if (!(tid & 1)) hs2[tid>>1] = (uint)f2b(hn) | (((uint)f2b(hn1)) << 16);
      float pv = hn * wfc_t;
      #pragma unroll
      for (int off=1; off<64; off<<=1) pv += __shfl_xor(pv, off, 64);
      if ((tid & 63) == 0) red[tid >> 6] = pv;
    }
    __syncthreads();
    if (tid == 0){
      float dv = red[0] + red[1] + bfc0;
      deltas[b*32 + step] = fmaxf(dv, 0.f) + log1pf(__expf(-fabsf(dv)));
    }
  }
}

// ---------------- times construction + KL ----------------
__global__ __launch_bounds__(64) void k_final(
    const float* __restrict__ deltas, const int* __restrict__ num_pred,
    float* __restrict__ out)
{
  const int b = blockIdx.x, l = threadIdx.x;
  float d = (l < 32) ? deltas[b*32 + l] : 0.f;
  float c = d;
  #pragma unroll
  for (int off=1; off<32; off<<=1){
    float t = __shfl_up(c, off, 64);
    if (l >= off) c += t;
  }
  const int np = num_pred[b];
  float last = __shfl(c, np-1, 64);
  float denom = last + 1e-6f;
  float cjm = __shfl(c, (l==0 ? 0 : l-1), 64);
  float val = 0.f;
  if (l >= 1 && l <= 32 && (l-1) < np) val = cjm / denom;
  if (l == np + 1) val += 1.f;
  if (l < 34) out[(size_t)b*419 + l] = val;
  float ta = 0.f, tb = 0.f, tc = 0.f;
  for (int z = l; z < 128; z += 64){
    float ga = out[(size_t)b*419 + 162 + z];
    float tu = fmaxf(out[(size_t)b*419 + 290 + z], 1e-35f);
    ta += tu*tu; tb += ga*ga; tc += -2.f*logf(tu);
  }
  float v = ta + tb + tc;
  #pragma unroll
  for (int off=1; off<64; off<<=1) v += __shfl_xor(v, off, 64);
  if (l == 0) out[(size_t)b*419 + 418] = 0.5f*(v - 128.f);
}

extern "C" void kernel_launch(void* const* d_in, const int* in_sizes, int n_in,
                              void* d_out, int out_size, void* d_ws, size_t ws_size,
                              hipStream_t stream)
{
  (void)in_sizes; (void)n_in; (void)out_size; (void)ws_size;
  const float* d_t    = (const float*)d_in[0];
  const float* d_l    = (const float*)d_in[1];
  const int*   d_emb  = (const int*)  d_in[2];
  const int*   numprd = (const int*)  d_in[4];
  const float* poi    = (const float*)d_in[5];
  const float* W_time = (const float*)d_in[6];
  const float* W_space= (const float*)d_in[7];
  const float* agg    = (const float*)d_in[8];
  const float* Wqkv   = (const float*)d_in[9];
  const float* bqkv   = (const float*)d_in[10];
  const float* Wo     = (const float*)d_in[11];
  const float* bo     = (const float*)d_in[12];
  const float* ln1g   = (const float*)d_in[13];
  const float* ln1b   = (const float*)d_in[14];
  const float* W1     = (const float*)d_in[15];
  const float* b1     = (const float*)d_in[16];
  const float* W2     = (const float*)d_in[17];
  const float* b2     = (const float*)d_in[18];
  const float* ln2g   = (const float*)d_in[19];
  const float* ln2b   = (const float*)d_in[20];
  const float* Wg     = (const float*)d_in[21];
  const float* bg     = (const float*)d_in[22];
  const float* Wt     = (const float*)d_in[23];
  const float* bt     = (const float*)d_in[24];
  const float* Whh    = (const float*)d_in[26];
  const float* bih    = (const float*)d_in[27];
  const float* bhh    = (const float*)d_in[28];
  const float* Wfc    = (const float*)d_in[29];
  const float* bfc    = (const float*)d_in[30];
  float* out = (float*)d_out;

  char* ws = (char*)d_ws;
  size_t off = 0;
  auto alloc = [&](size_t bytes){ size_t o = off; off += (bytes + 255) & ~(size_t)255; return o; };
  ushort* xb    = (ushort*)(ws + alloc((size_t)MM*128*2));
  ushort* qkv   = (ushort*)(ws + alloc((size_t)MM*384*2));
  ushort* aob   = (ushort*)(ws + alloc((size_t)MM*128*2));
  ushort* hb    = (ushort*)(ws + alloc((size_t)MM*256*2));
  ushort* wqkvb = (ushort*)(ws + alloc((size_t)LL*384*128*2));
  ushort* wob   = (ushort*)(ws + alloc((size_t)LL*128*128*2));
  ushort* w1b   = (ushort*)(ws + alloc((size_t)LL*256*128*2));
  ushort* w2b   = (ushort*)(ws + alloc((size_t)LL*128*256*2));
  ushort* whhb  = (ushort*)(ws + alloc((size_t)384*128*2));
  float*  ctxws = (float*) (ws + alloc(128*128*4));
  float*  deltas= (float*) (ws + alloc(128*32*4));

  k_f2b<<<(LL*384*128+255)/256,256,0,stream>>>(Wqkv, wqkvb, LL*384*128);
  k_f2b<<<(LL*128*128+255)/256,256,0,stream>>>(Wo,   wob,   LL*128*128);
  k_f2b<<<(LL*256*128+255)/256,256,0,stream>>>(W1,   w1b,   LL*256*128);
  k_f2b<<<(LL*128*256+255)/256,256,0,stream>>>(W2,   w2b,   LL*128*256);
  k_f2b<<<(384*128+255)/256,256,0,stream>>>(Whh, whhb, 384*128);
  k_embed<<<(MM*DD)/256,256,0,stream>>>(d_t, d_l, d_emb, poi, W_time, W_space, agg, xb);

  for (int li = 0; li < LL; li++){
    dim3 gq(MM/64, 6);
    k_gemm<false,true><<<gq,256,0,stream>>>(xb, wqkvb + li*384*128, bqkv + li*384, qkv, 384, 128);
    k_attn<<<BB*HH,512,0,stream>>>(qkv, aob);
    k_gemm_ln<<<MM/64,256,0,stream>>>(aob, wob + li*128*128, bo + li*128, xb,
                                      ln1g + li*128, ln1b + li*128, 128);
    dim3 gf(MM/64, 4);
    k_gemm<true,true><<<gf,256,0,stream>>>(xb, w1b + li*256*128, b1 + li*256, hb, 256, 128);
    k_gemm_ln<<<MM/64,256,0,stream>>>(hb, w2b + li*128*256, b2 + li*128, xb,
                                      ln2g + li*128, ln2b + li*128, 256);
  }

  k_ctx<<<128,256,0,stream>>>(xb, Wg, bg, Wt, bt, out, ctxws);
  k_gru<<<128,384,0,stream>>>(ctxws, whhb, bih, bhh, Wfc, bfc, deltas);
  k_final<<<128,64,0,stream>>>(deltas, numprd, out);
}